// Round 1
// baseline (207.429 us; speedup 1.0000x reference)
//
#include <hip/hip_runtime.h>

#define POOLP 7
#define NB 8
#define IH 64
#define IW 64
#define NC 1024
#define NR 32

// One block per output pixel (r, b, py, px); 256 threads each handle one
// float4 of the 1024 channels. All four corner loads + the store are fully
// coalesced 4KB segments.
__global__ __launch_bounds__(256) void roi_align_kernel(
    const float* __restrict__ img,
    const int* __restrict__ rois,
    float* __restrict__ out)
{
    int pix = blockIdx.x;
    int px = pix % POOLP; pix /= POOLP;
    int py = pix % POOLP; pix /= POOLP;
    int b  = pix % NB;    pix /= NB;
    int r  = pix;

    int rx = rois[r * 4 + 0];
    int ry = rois[r * 4 + 1];
    int rw = rois[r * 4 + 2];
    int rh = rois[r * 4 + 3];

    // Replicate reference fp32 arithmetic exactly:
    // coord = (out + 0.5) * (size / 7) - 0.5
    float sx = (float)rw / (float)POOLP;
    float sy = (float)rh / (float)POOLP;
    float cx = ((float)px + 0.5f) * sx - 0.5f;
    float cy = ((float)py + 0.5f) * sy - 0.5f;
    float fx = floorf(cx);
    float fy = floorf(cy);
    // lo = max(floor, 0); hi = clip(ceil, 0, size-1); weight = coord - floor
    int x0 = max((int)fx, 0);
    int y0 = max((int)fy, 0);
    int x1 = min(max((int)ceilf(cx), 0), rw - 1);
    int y1 = min(max((int)ceilf(cy), 0), rh - 1);
    float wx = cx - fx;
    float wy = cy - fy;

    int X0 = rx + x0, X1 = rx + x1;
    int Y0 = ry + y0, Y1 = ry + y1;

    const float4* i00 = (const float4*)(img + (((size_t)b * IH + Y0) * IW + X0) * NC);
    const float4* i01 = (const float4*)(img + (((size_t)b * IH + Y0) * IW + X1) * NC);
    const float4* i10 = (const float4*)(img + (((size_t)b * IH + Y1) * IW + X0) * NC);
    const float4* i11 = (const float4*)(img + (((size_t)b * IH + Y1) * IW + X1) * NC);

    // Output layout: (((r*NB + b)*POOLP + py)*POOLP + px)*NC + c
    float4* o = (float4*)(out + ((((size_t)r * NB + b) * POOLP + py) * POOLP + px) * NC);

    int c4 = threadIdx.x;  // 0..255
    float4 v00 = i00[c4];
    float4 v01 = i01[c4];
    float4 v10 = i10[c4];
    float4 v11 = i11[c4];

    float4 res;
    {
        float top, bot;
        top = v00.x + (v01.x - v00.x) * wx;
        bot = v10.x + (v11.x - v10.x) * wx;
        res.x = top + (bot - top) * wy;
        top = v00.y + (v01.y - v00.y) * wx;
        bot = v10.y + (v11.y - v10.y) * wx;
        res.y = top + (bot - top) * wy;
        top = v00.z + (v01.z - v00.z) * wx;
        bot = v10.z + (v11.z - v10.z) * wx;
        res.z = top + (bot - top) * wy;
        top = v00.w + (v01.w - v00.w) * wx;
        bot = v10.w + (v11.w - v10.w) * wx;
        res.w = top + (bot - top) * wy;
    }
    o[c4] = res;
}

extern "C" void kernel_launch(void* const* d_in, const int* in_sizes, int n_in,
                              void* d_out, int out_size, void* d_ws, size_t ws_size,
                              hipStream_t stream) {
    const float* img = (const float*)d_in[0];
    const int* rois = (const int*)d_in[1];
    float* out = (float*)d_out;

    int nblocks = NR * NB * POOLP * POOLP;  // 12544
    roi_align_kernel<<<nblocks, 256, 0, stream>>>(img, rois, out);
}